// Round 7
// baseline (463.442 us; speedup 1.0000x reference)
//
#include <hip/hip_runtime.h>
#include <math.h>

#define TT   256   // timesteps
#define HH   64    // hidden
#define INw  46    // input size
#define NCLS 8     // classes
#define BB   4     // batch rows per scan block (grid 512 = 2 blocks/CU)
#define B2   8     // batch rows per epilogue block
#define CH   16    // staged timesteps per chunk
#define XS   80    // padded k-stride (shorts): 160B = 40 words ≡ 8 (mod 32) -> uniform 2-way bank aliasing (free)

typedef __attribute__((ext_vector_type(8))) short  short8v;  // 8 bf16
typedef __attribute__((ext_vector_type(4))) float  float4v;

__device__ __forceinline__ float frcp(float x) { return __builtin_amdgcn_rcpf(x); }
__device__ __forceinline__ float sigmoid_f(float x) { return frcp(1.f + __expf(-x)); }
__device__ __forceinline__ float tanh_f(float x) {
    float a = fabsf(x);
    float e = __expf(-2.f * a);
    float r = (1.f - e) * frcp(1.f + e);
    return x >= 0.f ? r : -r;
}
__device__ __forceinline__ float dot4(float4 w, float4 a, float acc) {
    acc = fmaf(w.x, a.x, acc);
    acc = fmaf(w.y, a.y, acc);
    acc = fmaf(w.z, a.z, acc);
    acc = fmaf(w.w, a.w, acc);
    return acc;
}

// float -> bf16 round-to-nearest-even
__device__ __forceinline__ unsigned short f2bf(float f) {
    unsigned int u = __float_as_uint(f);
    unsigned int r = u + 0x7FFFu + ((u >> 16) & 1u);
    return (unsigned short)(r >> 16);
}
__device__ __forceinline__ float bf2f(unsigned short h) {
    return __uint_as_float(((unsigned int)h) << 16);
}
__device__ __forceinline__ void split8(const float v[8], short8v& hi, short8v& lo) {
#pragma unroll
    for (int e = 0; e < 8; ++e) {
        unsigned short h = f2bf(v[e]);
        hi[e] = (short)h;
        lo[e] = (short)f2bf(v[e] - bf2f(h));
    }
}

#define MFMA16(A,B,C) __builtin_amdgcn_mfma_f32_16x16x32_bf16((A),(B),(C),0,0,0)

// ---------------------------------------------------------------------------
// MFMA forward LSTM scan. 512 blocks x 4 batch rows, 4 waves/block
// (2 blocks/CU -> 2 waves/SIMD for latency hiding; R6 was grid-limited).
// Wave w owns gate tiles at cols {16w, 64+16w, 128+16w, 192+16w} -> each
// lane's i/f/g/o share (row, unit): cell update fully in-lane.
// A-rows 4..15 alias rows 0..3 (row4 = c16&3); D rows alias the same way, so
// g==0 lanes and g==1 lanes hold identical h values -> g0 writes h_hi,
// g1 writes h_lo. x pre-split to bf16 hi/lo in LDS once per 16-step chunk;
// h crosses steps via hi/lo bf16 LDS tiles (parity dbuf), ds_read_b128
// fragments, ONE barrier per step. Split-bf16 (3-term) = fp32-class accuracy.
// NOTE (R3 lesson): never force a tight occupancy bucket.
// ---------------------------------------------------------------------------
__global__ __launch_bounds__(256, 1) void lstm_fwd_mfma(
    const float* __restrict__ x,     // (B,T,46)
    const float* __restrict__ Wih,   // (256,46)
    const float* __restrict__ Whh,   // (256,64)
    const float* __restrict__ bih,   // (256)
    const float* __restrict__ bhh,   // (256)
    float* __restrict__ hf_out)      // (B,64)
{
    __shared__ short x_hi[CH][BB][XS];   // 10 KB
    __shared__ short x_lo[CH][BB][XS];   // 10 KB
    __shared__ short h_hi[2][BB][XS];    // 1.25 KB
    __shared__ short h_lo[2][BB][XS];    // 1.25 KB

    const int j    = threadIdx.x;
    const int w    = j >> 6;        // wave id = unit-group
    const int l    = j & 63;
    const int g    = l >> 4;        // k-group within fragment
    const int c16  = l & 15;        // A row / B col within tile
    const int row4 = c16 & 3;       // real batch row (A rows 4..15 alias 0..3)
    const int b0   = blockIdx.x * BB;
    const int u    = 16 * w + c16;  // hidden unit owned by this lane

    // ---- weight fragments in registers (B operand: B[k][n] = W[n][k]) ----
    short8v whh_h[4][2], whh_l[4][2], wih_h[4][2], wih_l[4][2];
    float bias[4];
#pragma unroll
    for (int q = 0; q < 4; ++q) {
        const int n = 64 * q + u;
        bias[q] = bih[n] + bhh[n];
#pragma unroll
        for (int s = 0; s < 2; ++s) {
            float vh[8], vi[8];
#pragma unroll
            for (int e = 0; e < 8; ++e) {
                const int k = 32 * s + 8 * g + e;
                vh[e] = Whh[n * HH + k];
                const int kc = (k < INw) ? k : 0;
                const float t = Wih[n * INw + kc];
                vi[e] = (k < INw) ? t : 0.f;
            }
            split8(vh, whh_h[q][s], whh_l[q][s]);
            split8(vi, wih_h[q][s], wih_l[q][s]);
        }
    }

    // ---- zero LDS: h (both parities) and x (incl. k>=46 pad, zeroed once;
    //      staging only writes k<46, pad stays zero across chunks) ----
    for (int idx = j; idx < 2 * BB * XS; idx += 256) {
        (&h_hi[0][0][0])[idx] = 0;
        (&h_lo[0][0][0])[idx] = 0;
    }
    for (int idx = j; idx < CH * BB * XS; idx += 256) {
        (&x_hi[0][0][0])[idx] = 0;
        (&x_lo[0][0][0])[idx] = 0;
    }

    float cst[4]  = {0.f, 0.f, 0.f, 0.f};
    float hnew[4] = {0.f, 0.f, 0.f, 0.f};
    __syncthreads();

    for (int t0 = 0; t0 < TT; t0 += CH) {
        // ---- stage + pre-split x chunk (prev step barrier covers safety) ----
        for (int e = j; e < BB * CH * INw; e += 256) {
            const int r   = e / (CH * INw);
            const int rem = e - r * (CH * INw);
            const int t   = rem / INw;
            const int k   = rem - t * INw;
            const float v = x[((size_t)(b0 + r) * TT + t0 + t) * INw + k];
            const unsigned short hh = f2bf(v);
            x_hi[t][r][k] = (short)hh;
            x_lo[t][r][k] = (short)f2bf(v - bf2f(hh));
        }
        __syncthreads();

        for (int ts = 0; ts < CH; ++ts) {
            const int t = t0 + ts;

            // ---- fragments: direct b128 reads, zero conversion VALU ----
            const short* hrh = &h_hi[(t + 1) & 1][0][0];
            const short* hrl = &h_lo[(t + 1) & 1][0][0];
            const short8v axh0 = *(const short8v*)&x_hi[ts][row4][8 * g];
            const short8v axh1 = *(const short8v*)&x_hi[ts][row4][32 + 8 * g];
            const short8v axl0 = *(const short8v*)&x_lo[ts][row4][8 * g];
            const short8v axl1 = *(const short8v*)&x_lo[ts][row4][32 + 8 * g];
            const short8v ahh0 = *(const short8v*)(hrh + row4 * XS + 8 * g);
            const short8v ahh1 = *(const short8v*)(hrh + row4 * XS + 32 + 8 * g);
            const short8v ahl0 = *(const short8v*)(hrl + row4 * XS + 8 * g);
            const short8v ahl1 = *(const short8v*)(hrl + row4 * XS + 32 + 8 * g);

            // ---- 48 MFMA: z = x*Wih^T + h*Whh^T (split-bf16, 12/gate) ----
            float4v C[4];
            const float4v z4 = {0.f, 0.f, 0.f, 0.f};
#pragma unroll
            for (int q = 0; q < 4; ++q) C[q] = z4;
#pragma unroll
            for (int q = 0; q < 4; ++q) {
                C[q] = MFMA16(axh0, wih_h[q][0], C[q]);
                C[q] = MFMA16(axh1, wih_h[q][1], C[q]);
                C[q] = MFMA16(ahh0, whh_h[q][0], C[q]);
                C[q] = MFMA16(ahh1, whh_h[q][1], C[q]);
                C[q] = MFMA16(axh0, wih_l[q][0], C[q]);
                C[q] = MFMA16(axh1, wih_l[q][1], C[q]);
                C[q] = MFMA16(axl0, wih_h[q][0], C[q]);
                C[q] = MFMA16(axl1, wih_h[q][1], C[q]);
                C[q] = MFMA16(ahh0, whh_l[q][0], C[q]);
                C[q] = MFMA16(ahh1, whh_l[q][1], C[q]);
                C[q] = MFMA16(ahl0, whh_h[q][0], C[q]);
                C[q] = MFMA16(ahl1, whh_h[q][1], C[q]);
            }

            // ---- gates + cell update (in-lane; D row = 4g+r, col = u) ----
#pragma unroll
            for (int r = 0; r < 4; ++r) {
                const float ig = sigmoid_f(C[0][r] + bias[0]);
                const float fg = sigmoid_f(C[1][r] + bias[1]);
                const float gg = tanh_f   (C[2][r] + bias[2]);
                const float og = sigmoid_f(C[3][r] + bias[3]);
                cst[r]  = fmaf(fg, cst[r], ig * gg);
                hnew[r] = og * tanh_f(cst[r]);
            }

            // ---- write h: D rows alias mod 4, so g0/g1 lanes hold identical
            //      hnew -> g0 writes hi, g1 writes lo (split the store work)
            short* hwh = &h_hi[t & 1][0][0];
            short* hwl = &h_lo[t & 1][0][0];
            if (g == 0) {
#pragma unroll
                for (int r = 0; r < 4; ++r)
                    hwh[r * XS + u] = (short)f2bf(hnew[r]);
            } else if (g == 1) {
#pragma unroll
                for (int r = 0; r < 4; ++r) {
                    const unsigned short hh = f2bf(hnew[r]);
                    hwl[r * XS + u] = (short)f2bf(hnew[r] - bf2f(hh));
                }
            }
            __syncthreads();
        }
    }

    if (g == 0) {
#pragma unroll
        for (int r = 0; r < 4; ++r)
            hf_out[(size_t)(b0 + r) * HH + u] = hnew[r];
    }
}

// ---------------------------------------------------------------------------
// Epilogue: backward dir = ONE LSTM step on x[:,T-1,:] (h0=c0=0, Whh_b unused),
// then FC + softmax.
// ---------------------------------------------------------------------------
__global__ __launch_bounds__(256) void lstm_bwd_fc(
    const float* __restrict__ x,
    const float* __restrict__ Wih,
    const float* __restrict__ bih,
    const float* __restrict__ bhh,
    const float* __restrict__ fcW,
    const float* __restrict__ fcb,
    const float* __restrict__ hf,
    float* __restrict__ out)
{
    __shared__ float xl[B2][48];
    __shared__ float act[B2][256];
    __shared__ float hbl[B2][HH];

    const int j  = threadIdx.x;
    const int b0 = blockIdx.x * B2;

    for (int e = j; e < B2 * INw; e += 256) {
        int b = e / INw, i = e - b * INw;
        xl[b][i] = x[((size_t)(b0 + b) * TT + (TT - 1)) * INw + i];
    }
    if (j < B2) { xl[j][46] = 0.f; xl[j][47] = 0.f; }
    __syncthreads();

    float4 wih4[12];
#pragma unroll
    for (int ii = 0; ii < 11; ++ii)
        wih4[ii] = make_float4(Wih[j*INw + 4*ii + 0], Wih[j*INw + 4*ii + 1],
                               Wih[j*INw + 4*ii + 2], Wih[j*INw + 4*ii + 3]);
    wih4[11] = make_float4(Wih[j*INw + 44], Wih[j*INw + 45], 0.f, 0.f);
    const float bias = bih[j] + bhh[j];
    const bool  gate_is_tanh = ((j >> 6) == 2);

#pragma unroll
    for (int b = 0; b < B2; ++b) {
        float a = bias;
#pragma unroll
        for (int ii = 0; ii < 12; ++ii) {
            float4 xv = *(const float4*)&xl[b][4*ii];
            a = dot4(wih4[ii], xv, a);
        }
        act[b][j] = gate_is_tanh ? tanh_f(a) : sigmoid_f(a);
    }
    __syncthreads();

    for (int q = j; q < B2 * HH; q += 256) {
        int b = q >> 6, l = q & 63;
        float ig = act[b][l];
        float gg = act[b][128 + l];
        float og = act[b][192 + l];
        hbl[b][l] = og * tanh_f(ig * gg);
    }
    __syncthreads();

    if (j < B2 * NCLS) {
        int b = j >> 3, n = j & 7;
        float a = fcb[n];
        const float* hfr = hf + (size_t)(b0 + b) * HH;
#pragma unroll
        for (int l = 0; l < HH; ++l) {
            a = fmaf(fcW[n * 2 * HH + l],      hfr[l],    a);
            a = fmaf(fcW[n * 2 * HH + HH + l], hbl[b][l], a);
        }
        float m = a;
        m = fmaxf(m, __shfl_xor(m, 1, 8));
        m = fmaxf(m, __shfl_xor(m, 2, 8));
        m = fmaxf(m, __shfl_xor(m, 4, 8));
        float e = __expf(a - m);
        float s = e;
        s += __shfl_xor(s, 1, 8);
        s += __shfl_xor(s, 2, 8);
        s += __shfl_xor(s, 4, 8);
        out[(size_t)(b0 + b) * NCLS + n] = e / s;
    }
}

extern "C" void kernel_launch(void* const* d_in, const int* in_sizes, int n_in,
                              void* d_out, int out_size, void* d_ws, size_t ws_size,
                              hipStream_t stream) {
    const float* x     = (const float*)d_in[0];
    const float* Wih_f = (const float*)d_in[1];
    const float* Whh_f = (const float*)d_in[2];
    const float* bih_f = (const float*)d_in[3];
    const float* bhh_f = (const float*)d_in[4];
    const float* Wih_b = (const float*)d_in[5];
    // d_in[6] = Whh_b: unused — backward dir contributes only its first step (h0=0)
    const float* bih_b = (const float*)d_in[7];
    const float* bhh_b = (const float*)d_in[8];
    const float* fcW   = (const float*)d_in[9];
    const float* fcb   = (const float*)d_in[10];
    float* out = (float*)d_out;
    float* hf  = (float*)d_ws;   // 2048*64 fp32 = 512 KB scratch

    hipLaunchKernelGGL(lstm_fwd_mfma, dim3(2048 / BB), dim3(256), 0, stream,
                       x, Wih_f, Whh_f, bih_f, bhh_f, hf);
    hipLaunchKernelGGL(lstm_bwd_fc, dim3(2048 / B2), dim3(256), 0, stream,
                       x, Wih_b, bih_b, bhh_b, fcW, fcb, hf, out);
}

// Round 9
// 299.577 us; speedup vs baseline: 1.5470x; 1.5470x over previous
//
#include <hip/hip_runtime.h>
#include <math.h>

#define TT   256   // timesteps
#define HH   64    // hidden
#define INw  46    // input size
#define NCLS 8     // classes
#define BB   8     // batch rows per scan block (grid 256)
#define CH   4     // timesteps per chunk (zx pipeline granularity)
#define NCH  (TT / CH)
#define B2   8     // batch rows per epilogue block
#define XS   80    // short stride for x/h LDS rows (160B -> 2-way free aliasing)

typedef __attribute__((ext_vector_type(8))) short  short8v;  // 8 bf16
typedef __attribute__((ext_vector_type(4))) float  float4v;

__device__ __forceinline__ float frcp(float x) { return __builtin_amdgcn_rcpf(x); }
__device__ __forceinline__ float sigmoid_f(float x) { return frcp(1.f + __expf(-x)); }
__device__ __forceinline__ float tanh_f(float x) {
    float a = fabsf(x);
    float e = __expf(-2.f * a);
    float r = (1.f - e) * frcp(1.f + e);
    return x >= 0.f ? r : -r;
}
__device__ __forceinline__ float dot4(float4 w, float4 a, float acc) {
    acc = fmaf(w.x, a.x, acc);
    acc = fmaf(w.y, a.y, acc);
    acc = fmaf(w.z, a.z, acc);
    acc = fmaf(w.w, a.w, acc);
    return acc;
}

// float -> bf16 round-to-nearest-even
__device__ __forceinline__ unsigned short f2bf(float f) {
    unsigned int u = __float_as_uint(f);
    unsigned int r = u + 0x7FFFu + ((u >> 16) & 1u);
    return (unsigned short)(r >> 16);
}
__device__ __forceinline__ float bf2f(unsigned short h) {
    return __uint_as_float(((unsigned int)h) << 16);
}
__device__ __forceinline__ void split8(const float v[8], short8v& hi, short8v& lo) {
#pragma unroll
    for (int e = 0; e < 8; ++e) {
        unsigned short h = f2bf(v[e]);
        hi[e] = (short)h;
        lo[e] = (short)f2bf(v[e] - bf2f(h));
    }
}

#define MFMA16(A,B,C) __builtin_amdgcn_mfma_f32_16x16x32_bf16((A),(B),(C),0,0,0)

// ---------------------------------------------------------------------------
// Wave-specialized MFMA LSTM scan. 256 blocks x 8 batch rows, 8 waves/block
// (2 waves/SIMD: 1 consumer + 1 producer -> latency overlap WITHOUT the R7
// redundancy). Consumers (waves 0-3) run the recurrent path: 24 MFMA h-part
// per step with zx C-init from LDS, in-lane i/f/g/o gates, h via parity-dbuf
// hi/lo LDS. Producers (waves 4-7) stage x[c+1] and compute zx[c+1] =
// x*Wih^T with NON-aliased 16-row A-tiles (48 MFMA per 4-step chunk),
// double-buffered by chunk parity. One s_barrier per step syncs both.
// Numerics: identical 3-term split-bf16 products, fp32 accumulate.
// NOTE (R3 lesson): never force a tight occupancy bucket.
// ---------------------------------------------------------------------------
__global__ __launch_bounds__(512) void lstm_fwd_mfma(
    const float* __restrict__ x,     // (B,T,46)
    const float* __restrict__ Wih,   // (256,46)
    const float* __restrict__ Whh,   // (256,64)
    const float* __restrict__ bih,   // (256)
    const float* __restrict__ bhh,   // (256)
    float* __restrict__ hf_out)      // (B,64)
{
    __shared__ float zx[2][CH][4][HH][8];    // 64 KB  (chunk-parity dbuf)
    __shared__ short x_hi[2][CH][BB][XS];    // 5 KB
    __shared__ short x_lo[2][CH][BB][XS];    // 5 KB
    __shared__ short h_hi[2][BB][XS];        // 2.5 KB (step-parity dbuf)
    __shared__ short h_lo[2][BB][XS];        // 2.5 KB

    const int j    = threadIdx.x;
    const int w    = j >> 6;
    const int l    = j & 63;
    const int g    = l >> 4;
    const int c16  = l & 15;
    const int b0   = blockIdx.x * BB;
    const bool consumer = (w < 4);
    const int u    = 16 * (consumer ? w : (w - 4)) + c16;   // owned unit group
    const int r0p  = ((g & 1) * 4) ^ (u & 4);               // zx bank swizzle

    // ---- per-class weight fragments (disjoint live sets per wave class) ----
    short8v whh_h[4][2], whh_l[4][2];   // consumer only
    short8v wih_h[4][2], wih_l[4][2];   // producer only
    float bias[4];

    if (consumer) {
#pragma unroll
        for (int q = 0; q < 4; ++q) {
            const int n = 64 * q + u;
            bias[q] = bih[n] + bhh[n];
#pragma unroll
            for (int s = 0; s < 2; ++s) {
                float vh[8];
#pragma unroll
                for (int e = 0; e < 8; ++e)
                    vh[e] = Whh[n * HH + 32 * s + 8 * g + e];
                split8(vh, whh_h[q][s], whh_l[q][s]);
            }
        }
    } else {
#pragma unroll
        for (int q = 0; q < 4; ++q) {
            const int n = 64 * q + u;
#pragma unroll
            for (int s = 0; s < 2; ++s) {
                float vi[8];
#pragma unroll
                for (int e = 0; e < 8; ++e) {
                    const int k = 32 * s + 8 * g + e;
                    const float t = Wih[n * INw + ((k < INw) ? k : 0)];
                    vi[e] = (k < INw) ? t : 0.f;
                }
                split8(vi, wih_h[q][s], wih_l[q][s]);
            }
        }
    }

    // ---- zero h bufs and x bufs (incl. k>=46 pad; staging writes only k<46,
    //      pad stays zero across all chunks) ----
    {
        short* hh0 = &h_hi[0][0][0];
        short* hl0 = &h_lo[0][0][0];
        for (int idx = j; idx < 2 * BB * XS; idx += 512) {
            hh0[idx] = 0;
            hl0[idx] = 0;
        }
        short* xh0 = &x_hi[0][0][0][0];
        short* xl0 = &x_lo[0][0][0][0];
        for (int idx = j; idx < 2 * CH * BB * XS; idx += 512) {
            xh0[idx] = 0;
            xl0[idx] = 0;
        }
    }
    __syncthreads();

    // ---- prologue: stage chunk 0 (all 512 threads), then zx[0] ----
    for (int e = j; e < BB * CH * INw; e += 512) {
        const int r   = e / (CH * INw);
        const int rem = e - r * (CH * INw);
        const int tt  = rem / INw;
        const int k   = rem - tt * INw;
        const float v = x[((size_t)(b0 + r) * TT + tt) * INw + k];
        const unsigned short hh = f2bf(v);
        x_hi[0][tt][r][k] = (short)hh;
        x_lo[0][tt][r][k] = (short)f2bf(v - bf2f(hh));
    }
    __syncthreads();

    if (!consumer) {
#pragma unroll
        for (int tau = 0; tau < 2; ++tau) {
            const int trel = 2 * tau + (c16 >> 3);
            const int rr   = c16 & 7;
            const short* ph = &x_hi[0][trel][rr][0];
            const short* pl = &x_lo[0][trel][rr][0];
            const short8v axh0 = *(const short8v*)(ph + 8 * g);
            const short8v axh1 = *(const short8v*)(ph + 32 + 8 * g);
            const short8v axl0 = *(const short8v*)(pl + 8 * g);
            const short8v axl1 = *(const short8v*)(pl + 32 + 8 * g);
            const int tout = 2 * tau + (g >> 1);
#pragma unroll
            for (int q = 0; q < 4; ++q) {
                float4v C = {0.f, 0.f, 0.f, 0.f};
                C = MFMA16(axh0, wih_h[q][0], C);
                C = MFMA16(axh1, wih_h[q][1], C);
                C = MFMA16(axh0, wih_l[q][0], C);
                C = MFMA16(axh1, wih_l[q][1], C);
                C = MFMA16(axl0, wih_h[q][0], C);
                C = MFMA16(axl1, wih_h[q][1], C);
                *(float4v*)&zx[0][tout][q][u][r0p] = C;
            }
        }
    }

    float cst[4]  = {0.f, 0.f, 0.f, 0.f};
    float hnew[4] = {0.f, 0.f, 0.f, 0.f};
    __syncthreads();

    for (int c = 0; c < NCH; ++c) {
        const int cb = c & 1, nb = cb ^ 1;
        for (int s = 0; s < CH; ++s) {
            const int t = c * CH + s;
            if (consumer) {
                // ---- recurrent step: 24 MFMA + in-lane gates ----
                const short* hrh = &h_hi[(t + 1) & 1][0][0];
                const short* hrl = &h_lo[(t + 1) & 1][0][0];
                const int ro = (c16 & 7) * XS;
                const short8v ahh0 = *(const short8v*)(hrh + ro + 8 * g);
                const short8v ahh1 = *(const short8v*)(hrh + ro + 32 + 8 * g);
                const short8v ahl0 = *(const short8v*)(hrl + ro + 8 * g);
                const short8v ahl1 = *(const short8v*)(hrl + ro + 32 + 8 * g);

                float4v C[4];
#pragma unroll
                for (int q = 0; q < 4; ++q)
                    C[q] = *(const float4v*)&zx[cb][s][q][u][r0p];
#pragma unroll
                for (int q = 0; q < 4; ++q) {
                    C[q] = MFMA16(ahh0, whh_h[q][0], C[q]);
                    C[q] = MFMA16(ahh1, whh_h[q][1], C[q]);
                    C[q] = MFMA16(ahh0, whh_l[q][0], C[q]);
                    C[q] = MFMA16(ahh1, whh_l[q][1], C[q]);
                    C[q] = MFMA16(ahl0, whh_h[q][0], C[q]);
                    C[q] = MFMA16(ahl1, whh_h[q][1], C[q]);
                }
#pragma unroll
                for (int r = 0; r < 4; ++r) {
                    const float ig = sigmoid_f(C[0][r] + bias[0]);
                    const float fg = sigmoid_f(C[1][r] + bias[1]);
                    const float gg = tanh_f   (C[2][r] + bias[2]);
                    const float og = sigmoid_f(C[3][r] + bias[3]);
                    cst[r]  = fmaf(fg, cst[r], ig * gg);
                    hnew[r] = og * tanh_f(cst[r]);
                }
                short* hwh = &h_hi[t & 1][0][0];
                short* hwl = &h_lo[t & 1][0][0];
                if (g < 2) {
#pragma unroll
                    for (int r = 0; r < 4; ++r) {
                        const unsigned short hh = f2bf(hnew[r]);
                        hwh[(4 * g + r) * XS + u] = (short)hh;
                        hwl[(4 * g + r) * XS + u] = (short)f2bf(hnew[r] - bf2f(hh));
                    }
                }
            } else if (c + 1 < NCH) {
                if (s == 0) {
                    // ---- stage x[c+1] into parity buffer nb ----
                    const int base = (c + 1) * CH;
                    for (int e = j - 256; e < BB * CH * INw; e += 256) {
                        const int r   = e / (CH * INw);
                        const int rem = e - r * (CH * INw);
                        const int tt  = rem / INw;
                        const int k   = rem - tt * INw;
                        const float v = x[((size_t)(b0 + r) * TT + base + tt) * INw + k];
                        const unsigned short hh = f2bf(v);
                        x_hi[nb][tt][r][k] = (short)hh;
                        x_lo[nb][tt][r][k] = (short)f2bf(v - bf2f(hh));
                    }
                } else if (s <= 2) {
                    // ---- zx[c+1], A-tile tau = s-1 (24 MFMA) ----
                    const int tau  = s - 1;
                    const int trel = 2 * tau + (c16 >> 3);
                    const int rr   = c16 & 7;
                    const short* ph = &x_hi[nb][trel][rr][0];
                    const short* pl = &x_lo[nb][trel][rr][0];
                    const short8v axh0 = *(const short8v*)(ph + 8 * g);
                    const short8v axh1 = *(const short8v*)(ph + 32 + 8 * g);
                    const short8v axl0 = *(const short8v*)(pl + 8 * g);
                    const short8v axl1 = *(const short8v*)(pl + 32 + 8 * g);
                    const int tout = 2 * tau + (g >> 1);
#pragma unroll
                    for (int q = 0; q < 4; ++q) {
                        float4v C = {0.f, 0.f, 0.f, 0.f};
                        C = MFMA16(axh0, wih_h[q][0], C);
                        C = MFMA16(axh1, wih_h[q][1], C);
                        C = MFMA16(axh0, wih_l[q][0], C);
                        C = MFMA16(axh1, wih_l[q][1], C);
                        C = MFMA16(axl0, wih_h[q][0], C);
                        C = MFMA16(axl1, wih_h[q][1], C);
                        *(float4v*)&zx[nb][tout][q][u][r0p] = C;
                    }
                }
            }
            __syncthreads();
        }
    }

    if (consumer && g < 2) {
#pragma unroll
        for (int r = 0; r < 4; ++r)
            hf_out[(size_t)(b0 + 4 * g + r) * HH + u] = hnew[r];
    }
}

// ---------------------------------------------------------------------------
// Epilogue: backward dir = ONE LSTM step on x[:,T-1,:] (h0=c0=0, Whh_b unused),
// then FC + softmax.
// ---------------------------------------------------------------------------
__global__ __launch_bounds__(256) void lstm_bwd_fc(
    const float* __restrict__ x,
    const float* __restrict__ Wih,
    const float* __restrict__ bih,
    const float* __restrict__ bhh,
    const float* __restrict__ fcW,
    const float* __restrict__ fcb,
    const float* __restrict__ hf,
    float* __restrict__ out)
{
    __shared__ float xl[B2][48];
    __shared__ float act[B2][256];
    __shared__ float hbl[B2][HH];

    const int j  = threadIdx.x;
    const int b0 = blockIdx.x * B2;

    for (int e = j; e < B2 * INw; e += 256) {
        int b = e / INw, i = e - b * INw;
        xl[b][i] = x[((size_t)(b0 + b) * TT + (TT - 1)) * INw + i];
    }
    if (j < B2) { xl[j][46] = 0.f; xl[j][47] = 0.f; }
    __syncthreads();

    float4 wih4[12];
#pragma unroll
    for (int ii = 0; ii < 11; ++ii)
        wih4[ii] = make_float4(Wih[j*INw + 4*ii + 0], Wih[j*INw + 4*ii + 1],
                               Wih[j*INw + 4*ii + 2], Wih[j*INw + 4*ii + 3]);
    wih4[11] = make_float4(Wih[j*INw + 44], Wih[j*INw + 45], 0.f, 0.f);
    const float bias = bih[j] + bhh[j];
    const bool  gate_is_tanh = ((j >> 6) == 2);

#pragma unroll
    for (int b = 0; b < B2; ++b) {
        float a = bias;
#pragma unroll
        for (int ii = 0; ii < 12; ++ii) {
            float4 xv = *(const float4*)&xl[b][4*ii];
            a = dot4(wih4[ii], xv, a);
        }
        act[b][j] = gate_is_tanh ? tanh_f(a) : sigmoid_f(a);
    }
    __syncthreads();

    for (int q = j; q < B2 * HH; q += 256) {
        int b = q >> 6, l = q & 63;
        float ig = act[b][l];
        float gg = act[b][128 + l];
        float og = act[b][192 + l];
        hbl[b][l] = og * tanh_f(ig * gg);
    }
    __syncthreads();

    if (j < B2 * NCLS) {
        int b = j >> 3, n = j & 7;
        float a = fcb[n];
        const float* hfr = hf + (size_t)(b0 + b) * HH;
#pragma unroll
        for (int l = 0; l < HH; ++l) {
            a = fmaf(fcW[n * 2 * HH + l],      hfr[l],    a);
            a = fmaf(fcW[n * 2 * HH + HH + l], hbl[b][l], a);
        }
        float m = a;
        m = fmaxf(m, __shfl_xor(m, 1, 8));
        m = fmaxf(m, __shfl_xor(m, 2, 8));
        m = fmaxf(m, __shfl_xor(m, 4, 8));
        float e = __expf(a - m);
        float s = e;
        s += __shfl_xor(s, 1, 8);
        s += __shfl_xor(s, 2, 8);
        s += __shfl_xor(s, 4, 8);
        out[(size_t)(b0 + b) * NCLS + n] = e / s;
    }
}

extern "C" void kernel_launch(void* const* d_in, const int* in_sizes, int n_in,
                              void* d_out, int out_size, void* d_ws, size_t ws_size,
                              hipStream_t stream) {
    const float* x     = (const float*)d_in[0];
    const float* Wih_f = (const float*)d_in[1];
    const float* Whh_f = (const float*)d_in[2];
    const float* bih_f = (const float*)d_in[3];
    const float* bhh_f = (const float*)d_in[4];
    const float* Wih_b = (const float*)d_in[5];
    // d_in[6] = Whh_b: unused — backward dir contributes only its first step (h0=0)
    const float* bih_b = (const float*)d_in[7];
    const float* bhh_b = (const float*)d_in[8];
    const float* fcW   = (const float*)d_in[9];
    const float* fcb   = (const float*)d_in[10];
    float* out = (float*)d_out;
    float* hf  = (float*)d_ws;   // 2048*64 fp32 = 512 KB scratch

    hipLaunchKernelGGL(lstm_fwd_mfma, dim3(2048 / BB), dim3(512), 0, stream,
                       x, Wih_f, Whh_f, bih_f, bhh_f, hf);
    hipLaunchKernelGGL(lstm_bwd_fc, dim3(2048 / B2), dim3(256), 0, stream,
                       x, Wih_b, bih_b, bhh_b, fcW, fcb, hf, out);
}

// Round 10
// 256.764 us; speedup vs baseline: 1.8049x; 1.1667x over previous
//
#include <hip/hip_runtime.h>
#include <math.h>

#define TT   256   // timesteps
#define HH   64    // hidden
#define INw  46    // input size
#define NCLS 8     // classes
#define BB   8     // batch rows per scan block (grid 256)
#define CH   4     // timesteps per chunk
#define NCH  (TT / CH)
#define B2   8     // batch rows per epilogue block
#define XS   80    // short stride for x/h LDS rows (160B -> 2-way free aliasing)
#define XCHS 20    // f32 stride per unit in gate-exchange buffer (banks <=2-way, 16B-aligned)

typedef __attribute__((ext_vector_type(8))) short  short8v;  // 8 bf16
typedef __attribute__((ext_vector_type(4))) float  float4v;

__device__ __forceinline__ float frcp(float x) { return __builtin_amdgcn_rcpf(x); }
__device__ __forceinline__ float sigmoid_f(float x) { return frcp(1.f + __expf(-x)); }
__device__ __forceinline__ float tanh_f(float x) {
    float a = fabsf(x);
    float e = __expf(-2.f * a);
    float r = (1.f - e) * frcp(1.f + e);
    return x >= 0.f ? r : -r;
}
__device__ __forceinline__ float dot4(float4 w, float4 a, float acc) {
    acc = fmaf(w.x, a.x, acc);
    acc = fmaf(w.y, a.y, acc);
    acc = fmaf(w.z, a.z, acc);
    acc = fmaf(w.w, a.w, acc);
    return acc;
}

// float -> bf16 round-to-nearest-even
__device__ __forceinline__ unsigned short f2bf(float f) {
    unsigned int u = __float_as_uint(f);
    unsigned int r = u + 0x7FFFu + ((u >> 16) & 1u);
    return (unsigned short)(r >> 16);
}
__device__ __forceinline__ float bf2f(unsigned short h) {
    return __uint_as_float(((unsigned int)h) << 16);
}
__device__ __forceinline__ void split8(const float v[8], short8v& hi, short8v& lo) {
#pragma unroll
    for (int e = 0; e < 8; ++e) {
        unsigned short h = f2bf(v[e]);
        hi[e] = (short)h;
        lo[e] = (short)f2bf(v[e] - bf2f(h));
    }
}

#define MFMA16(A,B,C) __builtin_amdgcn_mfma_f32_16x16x32_bf16((A),(B),(C),0,0,0)

// ---------------------------------------------------------------------------
// Gate-split MFMA LSTM scan. 256 blocks x 8 batch rows, 12 waves (3/SIMD):
//   waves 0-3 (IF): i,f tiles of units 16w -> 12 MFMA, then (post mid-barrier)
//                   read exchanged (g~,o~), cell update, h write.
//   waves 4-7 (GO): g,o tiles -> 12 MFMA + tanh/sigmoid + f32 exchange write.
//   waves 8-11 (P): x staging (T14 issue-early/write-late) + zx = x*Wih^T
//                   (R9-verified producer code, single x buffer).
// Numerics identical to R9 (3-term split-bf16, fp32 accumulate).
// 2 barriers/step. Unified weight-fragment file keeps VGPR ~150 for 3/SIMD.
// ---------------------------------------------------------------------------
__global__ __launch_bounds__(768, 3) void lstm_fwd_mfma(
    const float* __restrict__ x,     // (B,T,46)
    const float* __restrict__ Wih,   // (256,46)
    const float* __restrict__ Whh,   // (256,64)
    const float* __restrict__ bih,   // (256)
    const float* __restrict__ bhh,   // (256)
    float* __restrict__ hf_out)      // (B,64)
{
    __shared__ float zx[2][CH][4][HH][8];    // 64 KB (chunk-parity dbuf)
    __shared__ short x_hi[CH][BB][XS];       // 5 KB  (single buffer)
    __shared__ short x_lo[CH][BB][XS];       // 5 KB
    __shared__ short h_hi[2][BB][XS];        // 2.5 KB (step-parity dbuf)
    __shared__ short h_lo[2][BB][XS];        // 2.5 KB
    __shared__ float xch[HH * XCHS];         // 5 KB gate exchange (g~,o~)

    const int j    = threadIdx.x;
    const int w    = j >> 6;
    const int l    = j & 63;
    const int g    = l >> 4;
    const int c16  = l & 15;
    const int b0   = blockIdx.x * BB;
    const int wl   = w & 3;
    const int u    = 16 * wl + c16;
    const int r0p  = ((g & 1) * 4) ^ (u & 4);
    const bool isP  = (w >= 8);
    const bool isGO = (w >= 4 && w < 8);
    const bool isIF = (w < 4);

    // ---- unified weight fragment file (role-dependent contents) ----
    // consumers: wf[tq]=Whh_hi, wf[2+tq]=Whh_lo (tq=tile 0,1)
    // producers: wf[q]=Wih_hi,  wf[4+q]=Wih_lo  (q=gate 0..3)
    short8v wf[8][2];
    float bias2[2] = {0.f, 0.f};
    if (!isP) {
        const int cb0 = isGO ? 128 : 0;
#pragma unroll
        for (int tq = 0; tq < 2; ++tq) {
            const int n = cb0 + 64 * tq + u;
            bias2[tq] = bih[n] + bhh[n];
#pragma unroll
            for (int s2 = 0; s2 < 2; ++s2) {
                float vh[8];
#pragma unroll
                for (int e = 0; e < 8; ++e)
                    vh[e] = Whh[n * HH + 32 * s2 + 8 * g + e];
                split8(vh, wf[tq][s2], wf[2 + tq][s2]);
            }
        }
    } else {
#pragma unroll
        for (int q = 0; q < 4; ++q) {
            const int n = 64 * q + u;
#pragma unroll
            for (int s2 = 0; s2 < 2; ++s2) {
                float vi[8];
#pragma unroll
                for (int e = 0; e < 8; ++e) {
                    const int k = 32 * s2 + 8 * g + e;
                    const float tval = Wih[n * INw + ((k < INw) ? k : 0)];
                    vi[e] = (k < INw) ? tval : 0.f;
                }
                split8(vi, wf[q][s2], wf[4 + q][s2]);
            }
        }
    }

    // zx producer burst (R9-verified body; x single buffer, parity arg)
    auto zx_burst = [&](int tau, int nbuf) {
        const int trel = 2 * tau + (c16 >> 3);
        const int rr   = c16 & 7;
        const short* ph = &x_hi[trel][rr][0];
        const short* pl = &x_lo[trel][rr][0];
        const short8v axh0 = *(const short8v*)(ph + 8 * g);
        const short8v axh1 = *(const short8v*)(ph + 32 + 8 * g);
        const short8v axl0 = *(const short8v*)(pl + 8 * g);
        const short8v axl1 = *(const short8v*)(pl + 32 + 8 * g);
        const int tout = 2 * tau + (g >> 1);
#pragma unroll
        for (int q = 0; q < 4; ++q) {
            float4v Cq = {0.f, 0.f, 0.f, 0.f};
            Cq = MFMA16(axh0, wf[q][0], Cq);
            Cq = MFMA16(axh1, wf[q][1], Cq);
            Cq = MFMA16(axh0, wf[4 + q][0], Cq);
            Cq = MFMA16(axh1, wf[4 + q][1], Cq);
            Cq = MFMA16(axl0, wf[q][0], Cq);
            Cq = MFMA16(axl1, wf[q][1], Cq);
            *(float4v*)&zx[nbuf][tout][q][u][r0p] = Cq;
        }
    };

    // ---- zero LDS (h both parities; x incl. k>=46 pad — staging only
    //      writes k<46 so the pad stays zero for all chunks) ----
    {
        short* p1 = &h_hi[0][0][0]; short* p2 = &h_lo[0][0][0];
        for (int idx = j; idx < 2 * BB * XS; idx += 768) { p1[idx] = 0; p2[idx] = 0; }
        short* p3 = &x_hi[0][0][0]; short* p4 = &x_lo[0][0][0];
        for (int idx = j; idx < CH * BB * XS; idx += 768) { p3[idx] = 0; p4[idx] = 0; }
    }
    __syncthreads();

    // ---- stage x chunk 0 (all threads) ----
    for (int e = j; e < BB * CH * INw; e += 768) {
        const int r   = e / (CH * INw);
        const int rem = e - r * (CH * INw);
        const int tt  = rem / INw;
        const int k   = rem - tt * INw;
        const float v = x[((size_t)(b0 + r) * TT + tt) * INw + k];
        const unsigned short hh = f2bf(v);
        x_hi[tt][r][k] = (short)hh;
        x_lo[tt][r][k] = (short)f2bf(v - bf2f(hh));
    }
    __syncthreads();

    // ---- prologue: zx[0] (producers) + issue global loads for chunk 1 ----
    float xhold[6];
    if (isP) {
        zx_burst(0, 0);
        zx_burst(1, 0);
#pragma unroll
        for (int it = 0; it < 6; ++it) {
            const int e = (j - 512) + 256 * it;
            if (e < BB * CH * INw) {
                const int r   = e / (CH * INw);
                const int rem = e - r * (CH * INw);
                const int tt  = rem / INw;
                const int k   = rem - tt * INw;
                xhold[it] = x[((size_t)(b0 + r) * TT + CH + tt) * INw + k];
            }
        }
    }

    float cst[4]  = {0.f, 0.f, 0.f, 0.f};
    float hnew[4] = {0.f, 0.f, 0.f, 0.f};
    __syncthreads();

    for (int c = 0; c < NCH; ++c) {
        const int cb = c & 1, nb = cb ^ 1;
#pragma unroll
        for (int s = 0; s < CH; ++s) {
            const int t = c * CH + s;
            float4v C0, C1;
            // ======== PHASE 1: MFMA (consumers) / zx + load-issue (P) ======
            if (!isP) {
                const short* hrh = &h_hi[(t + 1) & 1][0][0];
                const short* hrl = &h_lo[(t + 1) & 1][0][0];
                const int ro = (c16 & 7) * XS;
                const short8v ahh0 = *(const short8v*)(hrh + ro + 8 * g);
                const short8v ahh1 = *(const short8v*)(hrh + ro + 32 + 8 * g);
                const short8v ahl0 = *(const short8v*)(hrl + ro + 8 * g);
                const short8v ahl1 = *(const short8v*)(hrl + ro + 32 + 8 * g);
                const int q0 = isGO ? 2 : 0;
                C0 = *(const float4v*)&zx[cb][s][q0][u][r0p];
                C1 = *(const float4v*)&zx[cb][s][q0 + 1][u][r0p];
                float4v D0 = {0.f, 0.f, 0.f, 0.f};
                float4v D1 = {0.f, 0.f, 0.f, 0.f};
                C0 = MFMA16(ahh0, wf[0][0], C0);
                C1 = MFMA16(ahh0, wf[1][0], C1);
                D0 = MFMA16(ahl0, wf[0][0], D0);
                D1 = MFMA16(ahl0, wf[1][0], D1);
                C0 = MFMA16(ahh1, wf[0][1], C0);
                C1 = MFMA16(ahh1, wf[1][1], C1);
                D0 = MFMA16(ahl1, wf[0][1], D0);
                D1 = MFMA16(ahl1, wf[1][1], D1);
                D0 = MFMA16(ahh0, wf[2][0], D0);
                D1 = MFMA16(ahh0, wf[3][0], D1);
                D0 = MFMA16(ahh1, wf[2][1], D0);
                D1 = MFMA16(ahh1, wf[3][1], D1);
                C0 += D0;
                C1 += D1;
                if (isGO) {
                    float gt[4], ot[4];
#pragma unroll
                    for (int r = 0; r < 4; ++r) {
                        gt[r] = tanh_f(C0[r] + bias2[0]);
                        ot[r] = sigmoid_f(C1[r] + bias2[1]);
                    }
                    if (g < 2) {
                        float4v A, Bv;
                        A[0] = gt[0]; A[1] = ot[0]; A[2] = gt[1]; A[3] = ot[1];
                        Bv[0] = gt[2]; Bv[1] = ot[2]; Bv[2] = gt[3]; Bv[3] = ot[3];
                        float* p = &xch[u * XCHS + 8 * g];
                        *(float4v*)p = A;
                        *(float4v*)(p + 4) = Bv;
                    }
                }
            } else {
                if (s == 1 && c + 1 < NCH) {
                    zx_burst(0, nb);
                } else if (s == 3 && c + 2 < NCH) {
                    // T14: issue global loads for chunk c+2 (written next chunk s0)
#pragma unroll
                    for (int it = 0; it < 6; ++it) {
                        const int e = (j - 512) + 256 * it;
                        if (e < BB * CH * INw) {
                            const int r   = e / (CH * INw);
                            const int rem = e - r * (CH * INw);
                            const int tt  = rem / INw;
                            const int k   = rem - tt * INw;
                            xhold[it] = x[((size_t)(b0 + r) * TT + (c + 2) * CH + tt) * INw + k];
                        }
                    }
                }
            }
            __syncthreads();   // B1: exchange published
            // ======== PHASE 2: update (IF) / staging write + zx (P) ========
            if (isIF) {
                const float* p = &xch[u * XCHS + 8 * (g & 1)];
                const float4v A  = *(const float4v*)p;
                const float4v Bv = *(const float4v*)(p + 4);
                const float gv[4] = {A[0], A[2], Bv[0], Bv[2]};
                const float ov[4] = {A[1], A[3], Bv[1], Bv[3]};
#pragma unroll
                for (int r = 0; r < 4; ++r) {
                    const float iv = sigmoid_f(C0[r] + bias2[0]);
                    const float fv = sigmoid_f(C1[r] + bias2[1]);
                    cst[r]  = fmaf(fv, cst[r], iv * gv[r]);
                    hnew[r] = ov[r] * tanh_f(cst[r]);
                }
                // h write: g0->hi rows0-3, g1->hi rows4-7, g2->lo rows0-3, g3->lo rows4-7
                short* dst = (g & 2) ? &h_lo[t & 1][0][0] : &h_hi[t & 1][0][0];
                const bool lo = (g & 2) != 0;
#pragma unroll
                for (int r = 0; r < 4; ++r) {
                    const int row = 4 * (g & 1) + r;
                    const unsigned short hh = f2bf(hnew[r]);
                    const short val = lo ? (short)f2bf(hnew[r] - bf2f(hh)) : (short)hh;
                    dst[row * XS + u] = val;
                }
            } else if (isP) {
                if (s == 0 && c + 1 < NCH) {
                    // write held x for chunk c+1 (loads issued at (c-1, s3))
#pragma unroll
                    for (int it = 0; it < 6; ++it) {
                        const int e = (j - 512) + 256 * it;
                        if (e < BB * CH * INw) {
                            const int r   = e / (CH * INw);
                            const int rem = e - r * (CH * INw);
                            const int tt  = rem / INw;
                            const int k   = rem - tt * INw;
                            const unsigned short hh = f2bf(xhold[it]);
                            x_hi[tt][r][k] = (short)hh;
                            x_lo[tt][r][k] = (short)f2bf(xhold[it] - bf2f(hh));
                        }
                    }
                } else if (s == 2 && c + 1 < NCH) {
                    zx_burst(1, nb);
                }
            }
            __syncthreads();   // B2: h + x published
        }
    }

    if (isIF && g < 2) {
#pragma unroll
        for (int r = 0; r < 4; ++r)
            hf_out[(size_t)(b0 + 4 * g + r) * HH + u] = hnew[r];
    }
}

// ---------------------------------------------------------------------------
// Epilogue: backward dir = ONE LSTM step on x[:,T-1,:] (h0=c0=0, Whh_b unused),
// then FC + softmax.
// ---------------------------------------------------------------------------
__global__ __launch_bounds__(256) void lstm_bwd_fc(
    const float* __restrict__ x,
    const float* __restrict__ Wih,
    const float* __restrict__ bih,
    const float* __restrict__ bhh,
    const float* __restrict__ fcW,
    const float* __restrict__ fcb,
    const float* __restrict__ hf,
    float* __restrict__ out)
{
    __shared__ float xl[B2][48];
    __shared__ float act[B2][256];
    __shared__ float hbl[B2][HH];

    const int j  = threadIdx.x;
    const int b0 = blockIdx.x * B2;

    for (int e = j; e < B2 * INw; e += 256) {
        int b = e / INw, i = e - b * INw;
        xl[b][i] = x[((size_t)(b0 + b) * TT + (TT - 1)) * INw + i];
    }
    if (j < B2) { xl[j][46] = 0.f; xl[j][47] = 0.f; }
    __syncthreads();

    float4 wih4[12];
#pragma unroll
    for (int ii = 0; ii < 11; ++ii)
        wih4[ii] = make_float4(Wih[j*INw + 4*ii + 0], Wih[j*INw + 4*ii + 1],
                               Wih[j*INw + 4*ii + 2], Wih[j*INw + 4*ii + 3]);
    wih4[11] = make_float4(Wih[j*INw + 44], Wih[j*INw + 45], 0.f, 0.f);
    const float bias = bih[j] + bhh[j];
    const bool  gate_is_tanh = ((j >> 6) == 2);

#pragma unroll
    for (int b = 0; b < B2; ++b) {
        float a = bias;
#pragma unroll
        for (int ii = 0; ii < 12; ++ii) {
            float4 xv = *(const float4*)&xl[b][4*ii];
            a = dot4(wih4[ii], xv, a);
        }
        act[b][j] = gate_is_tanh ? tanh_f(a) : sigmoid_f(a);
    }
    __syncthreads();

    for (int q = j; q < B2 * HH; q += 256) {
        int b = q >> 6, ll = q & 63;
        float ig = act[b][ll];
        float gg = act[b][128 + ll];
        float og = act[b][192 + ll];
        hbl[b][ll] = og * tanh_f(ig * gg);
    }
    __syncthreads();

    if (j < B2 * NCLS) {
        int b = j >> 3, n = j & 7;
        float a = fcb[n];
        const float* hfr = hf + (size_t)(b0 + b) * HH;
#pragma unroll
        for (int ll = 0; ll < HH; ++ll) {
            a = fmaf(fcW[n * 2 * HH + ll],      hfr[ll],    a);
            a = fmaf(fcW[n * 2 * HH + HH + ll], hbl[b][ll], a);
        }
        float m = a;
        m = fmaxf(m, __shfl_xor(m, 1, 8));
        m = fmaxf(m, __shfl_xor(m, 2, 8));
        m = fmaxf(m, __shfl_xor(m, 4, 8));
        float e = __expf(a - m);
        float s = e;
        s += __shfl_xor(s, 1, 8);
        s += __shfl_xor(s, 2, 8);
        s += __shfl_xor(s, 4, 8);
        out[(size_t)(b0 + b) * NCLS + n] = e / s;
    }
}

extern "C" void kernel_launch(void* const* d_in, const int* in_sizes, int n_in,
                              void* d_out, int out_size, void* d_ws, size_t ws_size,
                              hipStream_t stream) {
    const float* x     = (const float*)d_in[0];
    const float* Wih_f = (const float*)d_in[1];
    const float* Whh_f = (const float*)d_in[2];
    const float* bih_f = (const float*)d_in[3];
    const float* bhh_f = (const float*)d_in[4];
    const float* Wih_b = (const float*)d_in[5];
    // d_in[6] = Whh_b: unused — backward dir contributes only its first step (h0=0)
    const float* bih_b = (const float*)d_in[7];
    const float* bhh_b = (const float*)d_in[8];
    const float* fcW   = (const float*)d_in[9];
    const float* fcb   = (const float*)d_in[10];
    float* out = (float*)d_out;
    float* hf  = (float*)d_ws;   // 2048*64 fp32 = 512 KB scratch

    hipLaunchKernelGGL(lstm_fwd_mfma, dim3(2048 / BB), dim3(768), 0, stream,
                       x, Wih_f, Whh_f, bih_f, bhh_f, hf);
    hipLaunchKernelGGL(lstm_bwd_fc, dim3(2048 / B2), dim3(256), 0, stream,
                       x, Wih_b, bih_b, bhh_b, fcW, fcb, hf, out);
}